// Round 1
// 387.506 us; speedup vs baseline: 1.2723x; 1.2723x over previous
//
#include <hip/hip_runtime.h>

// Problem constants (tiny-shakespeare bigram-ish transformer fwd)
#define VOCAB   65
#define NEMB    32
#define TBLK    8
#define NHEAD   4
#define HS      8
#define NB      131072

// ws layout (float offsets):
//   Qtab[8][65][32]  @ 0        (16640 floats)
//   Ktab[8][65][32]  @ 16640
//   Vtab[8][65][32]  @ 33280
//   WfB  fp16[32][32] @ 49920   (Wf^T: WfB[j][c] = Wf[c][j], 1024 halves = 512 floats)
//   WlB  fp16[80][32] @ 50432   (Wl^T zero-padded to 80 cols, 2560 halves = 1280 floats)
#define TABSZ   16640
#define WFB_OFF (3 * TABSZ)
#define WLB_OFF (3 * TABSZ + 512)

typedef _Float16 f16x8 __attribute__((ext_vector_type(8)));
typedef float    f32x4 __attribute__((ext_vector_type(4)));

// ---------------------------------------------------------------------------
// Kernel 1: build q/k/v tables over all (t, token) combos + fp16-pack Wf^T/Wl^T.
// ---------------------------------------------------------------------------
__global__ void build_tables(const float* __restrict__ tok_emb,
                             const float* __restrict__ pos_emb,
                             const float* __restrict__ Wq,
                             const float* __restrict__ Wk,
                             const float* __restrict__ Wv,
                             const float* __restrict__ Wf,
                             const float* __restrict__ Wl,
                             float* __restrict__ ws) {
    int e = blockIdx.x * blockDim.x + threadIdx.x;
    if (e < 3 * TABSZ) {
        int tab = e / TABSZ;
        int r   = e % TABSZ;
        int t   = r / (VOCAB * NEMB);
        int rem = r % (VOCAB * NEMB);
        int tok = rem / NEMB;
        int hd  = rem % NEMB;          // h*8 + d
        int h = hd >> 3, d = hd & 7;
        const float* W = (tab == 0) ? Wq : (tab == 1 ? Wk : Wv);
        float acc = 0.f;
        #pragma unroll
        for (int c = 0; c < NEMB; ++c) {
            float x = tok_emb[tok * NEMB + c] + pos_emb[t * NEMB + c];
            acc = fmaf(x, W[(h * NEMB + c) * HS + d], acc);
        }
        ws[tab * TABSZ + r] = acc;
    } else if (e < 3 * TABSZ + 1024) {
        // WfB[j][c] = Wf[c][j]  (B-operand: B[k=c][col=j])
        int i = e - 3 * TABSZ;
        int j = i >> 5, c = i & 31;
        ((_Float16*)(ws + WFB_OFF))[i] = (_Float16)Wf[c * NEMB + j];
    } else if (e < 3 * TABSZ + 1024 + 2560) {
        // WlB[j][c] = Wl[c][j] for j<65, else 0 (pad cols 65..79)
        int i = e - (3 * TABSZ + 1024);
        int j = i >> 5, c = i & 31;
        ((_Float16*)(ws + WLB_OFF))[i] =
            (_Float16)((j < VOCAB) ? Wl[c * VOCAB + j] : 0.f);
    }
}

// ---------------------------------------------------------------------------
// Kernel 2: fused attention (fp32 VALU) + FF + logits (fp16 MFMA).
// 256 threads = 4 waves; each wave owns 64 rows end-to-end.
// MFMA frag layouts (16x16x32_f16, m89/m91-verified family):
//   A: row = l&15, k = (l>>4)*8 + e   (8 contiguous k per lane)
//   B: col = l&15, k = (l>>4)*8 + e
//   D: col = l&15, row = (l>>4)*4 + j
// ---------------------------------------------------------------------------
__global__ __launch_bounds__(256, 4) void fused_lm(
        const int*   __restrict__ idx,
        const float* __restrict__ ws,
        const float* __restrict__ bfv,
        const float* __restrict__ blv,
        float*       __restrict__ out) {

    __shared__ int      sidx[256];
    __shared__ _Float16 Abuf[256][40];   // xatt rows, then ff rows (fp16), 80B stride
    __shared__ float    lbuf[4][1040];   // per-wave 16x65 logit tile

    const float* Qtab = ws;
    const float* Ktab = ws + TABSZ;
    const float* Vtab = ws + 2 * TABSZ;
    const _Float16* wfb = (const _Float16*)(ws + WFB_OFF);
    const _Float16* wlb = (const _Float16*)(ws + WLB_OFF);

    const int tid  = threadIdx.x;
    const int row0 = blockIdx.x * 256;

    sidx[tid] = idx[row0 + tid];
    __syncthreads();

    const int b_loc = tid >> 3;
    const int t     = tid & 7;

    // ---- gather q (32 floats, 128B-aligned row) ----
    const int tok_t = sidx[tid];
    float4 q[8];
    {
        const float4* qrow = (const float4*)(Qtab + (t * VOCAB + tok_t) * NEMB);
        #pragma unroll
        for (int i = 0; i < 8; ++i) q[i] = qrow[i];
    }

    // ---- pass 1: scores q.k, all s, all 4 heads (predicated) ----
    const float scale = 0.17677669529663687f;   // 32^-0.5 (n_embed, not hs)
    float wei[4][8];
    #pragma unroll
    for (int s = 0; s < 8; ++s) {
        const int toks = sidx[(b_loc << 3) | s];
        const float4* krow = (const float4*)(Ktab + (s * VOCAB + toks) * NEMB);
        #pragma unroll
        for (int h = 0; h < 4; ++h) {
            float4 ka = krow[2 * h], kb = krow[2 * h + 1];
            float4 qa = q[2 * h],    qb = q[2 * h + 1];
            float d = qa.x * ka.x + qa.y * ka.y + qa.z * ka.z + qa.w * ka.w
                    + qb.x * kb.x + qb.y * kb.y + qb.z * kb.z + qb.w * kb.w;
            wei[h][s] = (s <= t) ? d * scale : -__builtin_inff();
        }
    }

    // ---- causal softmax per head ----
    #pragma unroll
    for (int h = 0; h < 4; ++h) {
        float m = wei[h][0];
        #pragma unroll
        for (int s = 1; s < 8; ++s) m = fmaxf(m, wei[h][s]);
        float sum = 0.f;
        #pragma unroll
        for (int s = 0; s < 8; ++s) {
            float e = __expf(wei[h][s] - m);
            wei[h][s] = e;
            sum += e;
        }
        float inv = 1.f / sum;
        #pragma unroll
        for (int s = 0; s < 8; ++s) wei[h][s] *= inv;
    }

    // ---- pass 2: xatt = P @ V (concat heads) ----
    float xatt[32];
    #pragma unroll
    for (int i = 0; i < 32; ++i) xatt[i] = 0.f;
    #pragma unroll
    for (int s = 0; s < 8; ++s) {
        const int toks = sidx[(b_loc << 3) | s];
        const float4* vrow = (const float4*)(Vtab + (s * VOCAB + toks) * NEMB);
        #pragma unroll
        for (int h = 0; h < 4; ++h) {
            float4 va = vrow[2 * h], vb = vrow[2 * h + 1];
            float p = wei[h][s];
            xatt[h * 8 + 0] = fmaf(p, va.x, xatt[h * 8 + 0]);
            xatt[h * 8 + 1] = fmaf(p, va.y, xatt[h * 8 + 1]);
            xatt[h * 8 + 2] = fmaf(p, va.z, xatt[h * 8 + 2]);
            xatt[h * 8 + 3] = fmaf(p, va.w, xatt[h * 8 + 3]);
            xatt[h * 8 + 4] = fmaf(p, vb.x, xatt[h * 8 + 4]);
            xatt[h * 8 + 5] = fmaf(p, vb.y, xatt[h * 8 + 5]);
            xatt[h * 8 + 6] = fmaf(p, vb.z, xatt[h * 8 + 6]);
            xatt[h * 8 + 7] = fmaf(p, vb.w, xatt[h * 8 + 7]);
        }
    }

    // ---- pack xatt -> fp16 into own Abuf row ----
    {
        f16x8* arow = (f16x8*)&Abuf[tid][0];
        #pragma unroll
        for (int qd = 0; qd < 4; ++qd) {
            f16x8 v;
            #pragma unroll
            for (int e2 = 0; e2 < 8; ++e2) v[e2] = (_Float16)xatt[qd * 8 + e2];
            arow[qd] = v;
        }
    }
    __syncthreads();

    const int l  = tid & 63;
    const int w  = tid >> 6;
    const int lr = l & 15;      // A-row / B-col / D-col within tile
    const int lg = l >> 4;      // k/row group

    // ---- A fragments (4 row-tiles of this wave's 64 rows) ----
    f16x8 afr[4];
    #pragma unroll
    for (int rt = 0; rt < 4; ++rt)
        afr[rt] = *(const f16x8*)&Abuf[w * 64 + rt * 16 + lr][lg * 8];

    // ---- FF: 2 col-tiles of Wf; relu; fp16 back into Abuf ----
    f16x8 bwf0 = *(const f16x8*)&wfb[(0 * 16 + lr) * 32 + lg * 8];
    f16x8 bwf1 = *(const f16x8*)&wfb[(1 * 16 + lr) * 32 + lg * 8];
    const float bias0 = bfv[lr], bias1 = bfv[16 + lr];

    #pragma unroll
    for (int rt = 0; rt < 4; ++rt) {
        f32x4 a0 = {0.f, 0.f, 0.f, 0.f}, a1 = {0.f, 0.f, 0.f, 0.f};
        a0 = __builtin_amdgcn_mfma_f32_16x16x32_f16(afr[rt], bwf0, a0, 0, 0, 0);
        a1 = __builtin_amdgcn_mfma_f32_16x16x32_f16(afr[rt], bwf1, a1, 0, 0, 0);
        #pragma unroll
        for (int j = 0; j < 4; ++j) {
            int row = w * 64 + rt * 16 + lg * 4 + j;
            Abuf[row][lr]      = (_Float16)fmaxf(a0[j] + bias0, 0.f);
            Abuf[row][16 + lr] = (_Float16)fmaxf(a1[j] + bias1, 0.f);
        }
    }
    __syncthreads();

    // ---- ff fragments ----
    f16x8 ffr[4];
    #pragma unroll
    for (int rt = 0; rt < 4; ++rt)
        ffr[rt] = *(const f16x8*)&Abuf[w * 64 + rt * 16 + lr][lg * 8];

    // ---- Wl B-fragments (5 col-tiles, padded to 80) + biases ----
    f16x8 bwl[5];
    float lbias[5];
    #pragma unroll
    for (int ct = 0; ct < 5; ++ct) {
        bwl[ct] = *(const f16x8*)&wlb[(ct * 16 + lr) * 32 + lg * 8];
        int col = ct * 16 + lr;
        lbias[ct] = (col < VOCAB) ? blv[col] : 0.f;
    }

    // ---- logits per 16-row tile: MFMA -> LDS tile -> coalesced store ----
    const size_t blockBase = (size_t)blockIdx.x * (256 * VOCAB);
    float* lb = lbuf[w];

    for (int rt = 0; rt < 4; ++rt) {
        #pragma unroll
        for (int ct = 0; ct < 5; ++ct) {
            f32x4 acc = {0.f, 0.f, 0.f, 0.f};
            acc = __builtin_amdgcn_mfma_f32_16x16x32_f16(ffr[rt], bwl[ct], acc, 0, 0, 0);
            int col = ct * 16 + lr;
            if (col < VOCAB) {
                #pragma unroll
                for (int j = 0; j < 4; ++j)
                    lb[(lg * 4 + j) * VOCAB + col] = acc[j] + lbias[ct];
            }
        }
        __syncthreads();   // tile complete (intra-wave, but keeps compiler/waves honest)

        // 16 rows x 65 = 1040 floats = 260 float4, 64B-aligned contiguous
        const size_t outBase = blockBase + (size_t)(w * 64 + rt * 16) * VOCAB;
        #pragma unroll
        for (int i = 0; i < 4; ++i) {
            int p = i * 64 + l;
            f32x4 v4 = *(const f32x4*)&lb[p * 4];
            *(f32x4*)&out[outBase + p * 4] = v4;
        }
        if (l < 4) {
            int p = 256 + l;
            f32x4 v4 = *(const f32x4*)&lb[p * 4];
            *(f32x4*)&out[outBase + p * 4] = v4;
        }
        __syncthreads();   // protect tile buffer before next rt overwrites
    }
}

// ---------------------------------------------------------------------------
extern "C" void kernel_launch(void* const* d_in, const int* in_sizes, int n_in,
                              void* d_out, int out_size, void* d_ws, size_t ws_size,
                              hipStream_t stream) {
    const int*   idx     = (const int*)  d_in[0];
    const float* tok_emb = (const float*)d_in[1];
    const float* pos_emb = (const float*)d_in[2];
    const float* Wq      = (const float*)d_in[3];
    const float* Wk      = (const float*)d_in[4];
    const float* Wv      = (const float*)d_in[5];
    const float* Wf      = (const float*)d_in[6];
    const float* bf      = (const float*)d_in[7];
    const float* Wl      = (const float*)d_in[8];
    const float* bl      = (const float*)d_in[9];
    float* ws  = (float*)d_ws;
    float* out = (float*)d_out;

    // 49,920 table elems + 1,024 WfB halves + 2,560 WlB halves = 53,504 threads
    hipLaunchKernelGGL(build_tables, dim3(209), dim3(256), 0, stream,
                       tok_emb, pos_emb, Wq, Wk, Wv, Wf, Wl, ws);
    // 131072*8 rows / 256 threads = 4096 blocks
    hipLaunchKernelGGL(fused_lm, dim3(4096), dim3(256), 0, stream,
                       idx, ws, bf, bl, out);
}

// Round 2
// 375.211 us; speedup vs baseline: 1.3140x; 1.0328x over previous
//
#include <hip/hip_runtime.h>

// Problem constants (tiny-shakespeare bigram-ish transformer fwd)
#define VOCAB   65
#define NEMB    32
#define NHEAD   4
#define HS      8

// ws layout (float offsets):
//   Qtab[8][65][32]   @ 0        (16640 floats)
//   Ktab[8][65][32]   @ 16640
//   Vtab[8][65][32]   @ 33280
//   WfB  fp16[32][32] @ 49920    (Wf^T, 1024 halves = 512 floats)
//   WlB  fp16[80][32] @ 50432    (Wl^T zero-padded to 80 cols, 2560 halves = 1280 floats)
//   Etab float4[8*65*8*65] @ 51712   (exp(q.k*scale) per head; 4.33 MB, optional)
#define TABSZ    16640
#define WFB_OFF  (3 * TABSZ)
#define WLB_OFF  (3 * TABSZ + 512)
#define ETAB_OFF (3 * TABSZ + 512 + 1280)          // 51712 floats
#define ETAB_N   (8 * VOCAB * 8 * VOCAB)           // 270400 float4 entries
#define NEED_WS_BYTES ((size_t)(ETAB_OFF + 4 * ETAB_N) * 4)   // ~4.53 MB

typedef _Float16 f16x8 __attribute__((ext_vector_type(8)));
typedef float    f32x4 __attribute__((ext_vector_type(4)));

// Wave-scope fence: all LDS/sidx/lbuf/Abuf traffic in fused_lm is wave-private,
// so full __syncthreads (which drains vmcnt(0) -> exposes store latency) is
// never needed. lgkmcnt(0) + sched_barrier gives intra-wave LDS ordering
// (rule #18: inline-asm waitcnt needs a sched_barrier to pin compiler order).
__device__ __forceinline__ void wave_fence() {
    __builtin_amdgcn_sched_barrier(0);
    asm volatile("s_waitcnt lgkmcnt(0)" ::: "memory");
    __builtin_amdgcn_sched_barrier(0);
}

// ---------------------------------------------------------------------------
// Kernel 1: build q/k/v tables over all (t, token) combos + fp16-pack Wf^T/Wl^T.
// ---------------------------------------------------------------------------
__global__ void build_tables(const float* __restrict__ tok_emb,
                             const float* __restrict__ pos_emb,
                             const float* __restrict__ Wq,
                             const float* __restrict__ Wk,
                             const float* __restrict__ Wv,
                             const float* __restrict__ Wf,
                             const float* __restrict__ Wl,
                             float* __restrict__ ws) {
    int e = blockIdx.x * blockDim.x + threadIdx.x;
    if (e < 3 * TABSZ) {
        int tab = e / TABSZ;
        int r   = e % TABSZ;
        int t   = r / (VOCAB * NEMB);
        int rem = r % (VOCAB * NEMB);
        int tok = rem / NEMB;
        int hd  = rem % NEMB;          // h*8 + d
        int h = hd >> 3, d = hd & 7;
        const float* W = (tab == 0) ? Wq : (tab == 1 ? Wk : Wv);
        float acc = 0.f;
        #pragma unroll
        for (int c = 0; c < NEMB; ++c) {
            float x = tok_emb[tok * NEMB + c] + pos_emb[t * NEMB + c];
            acc = fmaf(x, W[(h * NEMB + c) * HS + d], acc);
        }
        ws[tab * TABSZ + r] = acc;
    } else if (e < 3 * TABSZ + 1024) {
        int i = e - 3 * TABSZ;
        int j = i >> 5, c = i & 31;
        ((_Float16*)(ws + WFB_OFF))[i] = (_Float16)Wf[c * NEMB + j];
    } else if (e < 3 * TABSZ + 1024 + 2560) {
        int i = e - (3 * TABSZ + 1024);
        int j = i >> 5, c = i & 31;
        ((_Float16*)(ws + WLB_OFF))[i] =
            (_Float16)((j < VOCAB) ? Wl[c * VOCAB + j] : 0.f);
    }
}

// ---------------------------------------------------------------------------
// Kernel 1b: Etab[t][tok_t][s][tok_s][h] = exp(q(t,tok_t).k(s,tok_s) * scale).
// Scores are O(1e-5) (0.02-scale weights), so exp without max-subtraction is
// exact-to-rounding; softmax = E/sum(E) over s<=t.
// ---------------------------------------------------------------------------
__global__ void build_etab(float* __restrict__ ws) {
    int e = blockIdx.x * blockDim.x + threadIdx.x;
    if (e >= ETAB_N) return;
    int tok_s = e % VOCAB;
    int s     = (e / VOCAB) & 7;
    int tok_t = (e / (VOCAB * 8)) % VOCAB;
    int t     =  e / (VOCAB * 8 * VOCAB);
    const float* qrow = ws + (t * VOCAB + tok_t) * NEMB;
    const float* krow = ws + TABSZ + (s * VOCAB + tok_s) * NEMB;
    const float scale = 0.17677669529663687f;      // 32^-0.5
    f32x4 r;
    #pragma unroll
    for (int h = 0; h < 4; ++h) {
        float d = 0.f;
        #pragma unroll
        for (int dd = 0; dd < 8; ++dd)
            d = fmaf(qrow[h * 8 + dd], krow[h * 8 + dd], d);
        r[h] = expf(d * scale);
    }
    ((f32x4*)(ws + ETAB_OFF))[e] = r;
}

// ---------------------------------------------------------------------------
// Kernel 2: fused attention + FF + logits (fp16 MFMA). Entirely wave-private:
// no __syncthreads anywhere -> global stores never drain, waves decoupled.
// ETAB=true: attention weights via gathered exp-table (no q/k loads, no exp).
// ---------------------------------------------------------------------------
template<bool ETAB>
__global__ __launch_bounds__(256, 4) void fused_lm(
        const int*   __restrict__ idx,
        const float* __restrict__ ws,
        const float* __restrict__ bfv,
        const float* __restrict__ blv,
        float*       __restrict__ out) {

    __shared__ int      sidx[256];
    __shared__ _Float16 Abuf[256][40];   // xatt rows, then ff rows (fp16)
    __shared__ float    lbuf[4][1040];   // per-wave 16x65 logit tile

    const float* Vtab = ws + 2 * TABSZ;
    const _Float16* wfb = (const _Float16*)(ws + WFB_OFF);
    const _Float16* wlb = (const _Float16*)(ws + WLB_OFF);

    const int tid  = threadIdx.x;
    const int row0 = blockIdx.x * 256;

    sidx[tid] = idx[row0 + tid];
    wave_fence();                        // sidx reads are same-wave only

    const int b_loc = tid >> 3;
    const int t     = tid & 7;
    const int tok_t = sidx[tid];

    float p[4][8];                       // attention weights [head][s]

    if constexpr (ETAB) {
        const float* Etab = ws + ETAB_OFF;
        #pragma unroll
        for (int s = 0; s < 8; ++s) {
            const int toks = sidx[(b_loc << 3) | s];
            const f32x4 ev = *(const f32x4*)(
                Etab + (size_t)((((t * VOCAB + tok_t) * 8 + s) * VOCAB + toks)) * 4);
            const bool ok = (s <= t);
            #pragma unroll
            for (int h = 0; h < 4; ++h) p[h][s] = ok ? ev[h] : 0.f;
        }
        #pragma unroll
        for (int h = 0; h < 4; ++h) {
            float sum = p[h][0];
            #pragma unroll
            for (int s = 1; s < 8; ++s) sum += p[h][s];
            float inv = 1.f / sum;
            #pragma unroll
            for (int s = 0; s < 8; ++s) p[h][s] *= inv;
        }
    } else {
        const float* Qtab = ws;
        const float* Ktab = ws + TABSZ;
        float4 q[8];
        const float4* qrow = (const float4*)(Qtab + (t * VOCAB + tok_t) * NEMB);
        #pragma unroll
        for (int i = 0; i < 8; ++i) q[i] = qrow[i];

        const float scale = 0.17677669529663687f;
        #pragma unroll
        for (int s = 0; s < 8; ++s) {
            const int toks = sidx[(b_loc << 3) | s];
            const float4* krow = (const float4*)(Ktab + (s * VOCAB + toks) * NEMB);
            #pragma unroll
            for (int h = 0; h < 4; ++h) {
                float4 ka = krow[2 * h], kb = krow[2 * h + 1];
                float4 qa = q[2 * h],    qb = q[2 * h + 1];
                float d = qa.x * ka.x + qa.y * ka.y + qa.z * ka.z + qa.w * ka.w
                        + qb.x * kb.x + qb.y * kb.y + qb.z * kb.z + qb.w * kb.w;
                p[h][s] = (s <= t) ? d * scale : -__builtin_inff();
            }
        }
        #pragma unroll
        for (int h = 0; h < 4; ++h) {
            float m = p[h][0];
            #pragma unroll
            for (int s = 1; s < 8; ++s) m = fmaxf(m, p[h][s]);
            float sum = 0.f;
            #pragma unroll
            for (int s = 0; s < 8; ++s) {
                float e = __expf(p[h][s] - m);
                p[h][s] = e;
                sum += e;
            }
            float inv = 1.f / sum;
            #pragma unroll
            for (int s = 0; s < 8; ++s) p[h][s] *= inv;
        }
    }

    // ---- PV: xatt = P @ V (concat heads) ----
    float xatt[32];
    #pragma unroll
    for (int i = 0; i < 32; ++i) xatt[i] = 0.f;
    #pragma unroll
    for (int s = 0; s < 8; ++s) {
        const int toks = sidx[(b_loc << 3) | s];
        const float4* vrow = (const float4*)(Vtab + (s * VOCAB + toks) * NEMB);
        #pragma unroll
        for (int h = 0; h < 4; ++h) {
            float4 va = vrow[2 * h], vb = vrow[2 * h + 1];
            float pp = p[h][s];
            xatt[h * 8 + 0] = fmaf(pp, va.x, xatt[h * 8 + 0]);
            xatt[h * 8 + 1] = fmaf(pp, va.y, xatt[h * 8 + 1]);
            xatt[h * 8 + 2] = fmaf(pp, va.z, xatt[h * 8 + 2]);
            xatt[h * 8 + 3] = fmaf(pp, va.w, xatt[h * 8 + 3]);
            xatt[h * 8 + 4] = fmaf(pp, vb.x, xatt[h * 8 + 4]);
            xatt[h * 8 + 5] = fmaf(pp, vb.y, xatt[h * 8 + 5]);
            xatt[h * 8 + 6] = fmaf(pp, vb.z, xatt[h * 8 + 6]);
            xatt[h * 8 + 7] = fmaf(pp, vb.w, xatt[h * 8 + 7]);
        }
    }

    // ---- pack xatt -> fp16 into own Abuf row ----
    {
        f16x8* arow = (f16x8*)&Abuf[tid][0];
        #pragma unroll
        for (int qd = 0; qd < 4; ++qd) {
            f16x8 v;
            #pragma unroll
            for (int e2 = 0; e2 < 8; ++e2) v[e2] = (_Float16)xatt[qd * 8 + e2];
            arow[qd] = v;
        }
    }
    wave_fence();                        // Abuf rows are wave-private

    const int l  = tid & 63;
    const int w  = tid >> 6;
    const int lr = l & 15;      // A-row / B-col / D-col within tile
    const int lg = l >> 4;      // k/row group

    // ---- A fragments (4 row-tiles of this wave's 64 rows) ----
    f16x8 afr[4];
    #pragma unroll
    for (int rt = 0; rt < 4; ++rt)
        afr[rt] = *(const f16x8*)&Abuf[w * 64 + rt * 16 + lr][lg * 8];

    // ---- FF: 2 col-tiles of Wf; relu; fp16 back into Abuf ----
    f16x8 bwf0 = *(const f16x8*)&wfb[(0 * 16 + lr) * 32 + lg * 8];
    f16x8 bwf1 = *(const f16x8*)&wfb[(1 * 16 + lr) * 32 + lg * 8];
    const float bias0 = bfv[lr], bias1 = bfv[16 + lr];

    #pragma unroll
    for (int rt = 0; rt < 4; ++rt) {
        f32x4 a0 = {0.f, 0.f, 0.f, 0.f}, a1 = {0.f, 0.f, 0.f, 0.f};
        a0 = __builtin_amdgcn_mfma_f32_16x16x32_f16(afr[rt], bwf0, a0, 0, 0, 0);
        a1 = __builtin_amdgcn_mfma_f32_16x16x32_f16(afr[rt], bwf1, a1, 0, 0, 0);
        #pragma unroll
        for (int j = 0; j < 4; ++j) {
            int row = w * 64 + rt * 16 + lg * 4 + j;
            Abuf[row][lr]      = (_Float16)fmaxf(a0[j] + bias0, 0.f);
            Abuf[row][16 + lr] = (_Float16)fmaxf(a1[j] + bias1, 0.f);
        }
    }
    wave_fence();

    // ---- ff fragments ----
    f16x8 ffr[4];
    #pragma unroll
    for (int rt = 0; rt < 4; ++rt)
        ffr[rt] = *(const f16x8*)&Abuf[w * 64 + rt * 16 + lr][lg * 8];

    // ---- Wl B-fragments (5 col-tiles, padded to 80) + biases ----
    f16x8 bwl[5];
    float lbias[5];
    #pragma unroll
    for (int ct = 0; ct < 5; ++ct) {
        bwl[ct] = *(const f16x8*)&wlb[(ct * 16 + lr) * 32 + lg * 8];
        int col = ct * 16 + lr;
        lbias[ct] = (col < VOCAB) ? blv[col] : 0.f;
    }

    // ---- logits per 16-row tile: MFMA -> per-wave LDS tile -> coalesced
    //      store. No barriers: stores stay in flight (vmcnt never drained). ----
    const size_t blockBase = (size_t)blockIdx.x * (256 * VOCAB);
    float* lb = lbuf[w];

    for (int rt = 0; rt < 4; ++rt) {
        #pragma unroll
        for (int ct = 0; ct < 5; ++ct) {
            f32x4 acc = {0.f, 0.f, 0.f, 0.f};
            acc = __builtin_amdgcn_mfma_f32_16x16x32_f16(ffr[rt], bwl[ct], acc, 0, 0, 0);
            int col = ct * 16 + lr;
            if (col < VOCAB) {
                #pragma unroll
                for (int j = 0; j < 4; ++j)
                    lb[(lg * 4 + j) * VOCAB + col] = acc[j] + lbias[ct];
            }
        }
        wave_fence();                    // tile writes visible to own wave

        // 16 rows x 65 = 1040 floats = 260 float4, 64B-aligned contiguous
        const size_t outBase = blockBase + (size_t)(w * 64 + rt * 16) * VOCAB;
        #pragma unroll
        for (int i = 0; i < 4; ++i) {
            int pidx = i * 64 + l;
            f32x4 v4 = *(const f32x4*)&lb[pidx * 4];
            *(f32x4*)&out[outBase + pidx * 4] = v4;
        }
        if (l < 4) {
            int pidx = 256 + l;
            f32x4 v4 = *(const f32x4*)&lb[pidx * 4];
            *(f32x4*)&out[outBase + pidx * 4] = v4;
        }
        wave_fence();                    // reads returned before next rt rewrites
    }
}

// ---------------------------------------------------------------------------
extern "C" void kernel_launch(void* const* d_in, const int* in_sizes, int n_in,
                              void* d_out, int out_size, void* d_ws, size_t ws_size,
                              hipStream_t stream) {
    const int*   idx     = (const int*)  d_in[0];
    const float* tok_emb = (const float*)d_in[1];
    const float* pos_emb = (const float*)d_in[2];
    const float* Wq      = (const float*)d_in[3];
    const float* Wk      = (const float*)d_in[4];
    const float* Wv      = (const float*)d_in[5];
    const float* Wf      = (const float*)d_in[6];
    const float* bf      = (const float*)d_in[7];
    const float* Wl      = (const float*)d_in[8];
    const float* bl      = (const float*)d_in[9];
    float* ws  = (float*)d_ws;
    float* out = (float*)d_out;

    // 49,920 table elems + 1,024 WfB halves + 2,560 WlB halves = 53,504 threads
    hipLaunchKernelGGL(build_tables, dim3(209), dim3(256), 0, stream,
                       tok_emb, pos_emb, Wq, Wk, Wv, Wf, Wl, ws);

    if (ws_size >= NEED_WS_BYTES) {
        // 270,400 exp-table entries
        hipLaunchKernelGGL(build_etab, dim3(1057), dim3(256), 0, stream, ws);
        hipLaunchKernelGGL(fused_lm<true>, dim3(4096), dim3(256), 0, stream,
                           idx, ws, bf, bl, out);
    } else {
        hipLaunchKernelGGL(fused_lm<false>, dim3(4096), dim3(256), 0, stream,
                           idx, ws, bf, bl, out);
    }
}